// Round 10
// baseline (933.349 us; speedup 1.0000x reference)
//
#include <hip/hip_runtime.h>

#define NN 50000
#define NE 800000
#define NL 3

typedef __bf16 bf16x8 __attribute__((ext_vector_type(8)));
typedef float f32x16 __attribute__((ext_vector_type(16)));
typedef unsigned int u32x4 __attribute__((ext_vector_type(4)));

// ---------------- zero degree array ----------------
__global__ __launch_bounds__(256) void k_zero(float* __restrict__ deg) {
  int i = blockIdx.x * 256 + threadIdx.x;
  if (i < NN) deg[i] = 0.f;
}

// ---------------- zero agg (fp32 accumulator for fused aggregation) ----------------
__global__ __launch_bounds__(256) void k_zagg(float* __restrict__ agg) {
  int i = blockIdx.x * 256 + threadIdx.x;
  if (i < NN * 16) ((float4*)agg)[i] = make_float4(0.f, 0.f, 0.f, 0.f);
}

// ---------------- degree histogram ----------------
__global__ __launch_bounds__(256) void k_deg(const int* __restrict__ trg,
                                             float* __restrict__ deg) {
  int e = blockIdx.x * 256 + threadIdx.x;
  if (e < NE) atomicAdd(&deg[trg[e]], 1.0f);
}

// ---------------- exclusive scan of degrees -> CSR row starts ----------------
__global__ __launch_bounds__(1024) void k_scan(const float* __restrict__ deg,
                                               int* __restrict__ rowstart,
                                               int* __restrict__ cursor) {
  __shared__ int part[1024];
  int t = threadIdx.x;
  int t0 = t * 49, t1 = min(t0 + 49, NN);
  int s = 0;
  for (int i = t0; i < t1; i++) s += (int)deg[i];
  part[t] = s;
  __syncthreads();
  for (int off = 1; off < 1024; off <<= 1) {
    int vv = (t >= off) ? part[t - off] : 0;
    int v = part[t];
    __syncthreads();
    part[t] = v + vv;
    __syncthreads();
  }
  int run = part[t] - s;  // exclusive prefix
  for (int i = t0; i < t1; i++) {
    rowstart[i] = run;
    cursor[i] = run;
    run += (int)deg[i];
  }
  if (t == 1023) rowstart[NN] = NE;
}

// ---------------- CSR fill: bucket by trg; emit src/eid/trg per position ----------------
__global__ __launch_bounds__(256) void k_fill(const int* __restrict__ src,
                                              const int* __restrict__ trg,
                                              int* __restrict__ cursor,
                                              int* __restrict__ csr,
                                              int* __restrict__ eid,
                                              int* __restrict__ trgp) {
  int e = blockIdx.x * 256 + threadIdx.x;
  if (e < NE) {
    int tv = trg[e];
    int pos = atomicAdd(&cursor[tv], 1);
    csr[pos] = src[e];
    eid[pos] = e;
    trgp[pos] = tv;
  }
}

__device__ inline u32x4 pack8(const float* f) {
  u32x4 r;
  #pragma unroll
  for (int i = 0; i < 4; i++) {
    unsigned short lo = __builtin_bit_cast(unsigned short, (__bf16)f[2 * i]);
    unsigned short hi = __builtin_bit_cast(unsigned short, (__bf16)f[2 * i + 1]);
    r[i] = (unsigned)lo | ((unsigned)hi << 16);
  }
  return r;
}

__device__ inline float bflo(unsigned u) {
  return __builtin_bit_cast(float, u << 16);
}
__device__ inline float bfhi(unsigned u) {
  return __builtin_bit_cast(float, u & 0xffff0000u);
}

// ---------------- bf16 mirror of x_in (layer-0 gather source) ----------------
__global__ __launch_bounds__(256) void k_xmir(const float* __restrict__ x,
                                              unsigned short* __restrict__ xb) {
  int i = blockIdx.x * 256 + threadIdx.x;   // NN*8 items, 8 elems each
  if (i < NN * 8) {
    const float4* x4 = (const float4*)x;
    float4 a = x4[2 * i], b = x4[2 * i + 1];
    float f[8] = {a.x, a.y, a.z, a.w, b.x, b.y, b.z, b.w};
    ((u32x4*)xb)[i] = pack8(f);
  }
}

// ---------------- gather aggregation v3 (layer 0 only now) ----------------
__global__ __launch_bounds__(256) void k_agg(const unsigned short* __restrict__ xb,
                                             const int* __restrict__ rowstart,
                                             const int* __restrict__ csr,
                                             float* __restrict__ agg, int relu) {
  int i = blockIdx.x * 256 + threadIdx.x;
  if (i >= NN * 8) return;
  int n = i >> 3, q = i & 7;                 // chunk q: bf16 cols [8q, 8q+8)
  const u32x4* xq = (const u32x4*)xb;
  int b = rowstart[n], en = rowstart[n + 1];
  int nj = en - b;
  float acc[8] = {0.f, 0.f, 0.f, 0.f, 0.f, 0.f, 0.f, 0.f};
  u32x4 v0 = {}, v1 = {};
  if (nj > 0) v0 = xq[(size_t)csr[b] * 8 + q];
  if (nj > 1) v1 = xq[(size_t)csr[b + 1] * 8 + q];
  for (int j = 0; j < nj; j++) {
    u32x4 v = v0;
    v0 = v1;
    if (j + 2 < nj) v1 = xq[(size_t)csr[b + j + 2] * 8 + q];
    #pragma unroll
    for (int c = 0; c < 4; c++) {
      float lo = bflo(v[c]), hi = bfhi(v[c]);
      if (relu) { lo = fmaxf(lo, 0.f); hi = fmaxf(hi, 0.f); }
      acc[2 * c] += lo;
      acc[2 * c + 1] += hi;
    }
  }
  float inv = 1.0f / fmaxf((float)nj, 1.0f);
  float4 o0 = {acc[0] * inv, acc[1] * inv, acc[2] * inv, acc[3] * inv};
  float4 o1 = {acc[4] * inv, acc[5] * inv, acc[6] * inv, acc[7] * inv};
  float4* a4 = (float4*)agg;
  a4[(size_t)n * 16 + q * 2] = o0;
  a4[(size_t)n * 16 + q * 2 + 1] = o1;
}

// ---------------- node conv: xout = relu?(x)@Ws + agg@Wn + b (+ bf16 mirror) ----------------
__global__ __launch_bounds__(256) void k_conv(const float* __restrict__ x,
                                              const float* __restrict__ agg,
                                              const float* __restrict__ Ws,
                                              const float* __restrict__ Wn,
                                              const float* __restrict__ bc,
                                              float* __restrict__ xout,
                                              unsigned short* __restrict__ xb,
                                              int relu) {
  __shared__ float sWs[64 * 64];
  __shared__ float sWn[64 * 64];
  __shared__ float sx[4][64];
  __shared__ float sa[4][64];
  int tid = threadIdx.x;
  for (int i = tid; i < 4096; i += 256) { sWs[i] = Ws[i]; sWn[i] = Wn[i]; }
  int g = tid >> 6, lane = tid & 63;
  int n = blockIdx.x * 4 + g;
  float xv = x[(size_t)n * 64 + lane];
  if (relu) xv = fmaxf(xv, 0.f);
  sx[g][lane] = xv;
  sa[g][lane] = agg[(size_t)n * 64 + lane];
  __syncthreads();
  float acc = bc[lane];
  #pragma unroll
  for (int k = 0; k < 64; k++) {
    acc += sx[g][k] * sWs[k * 64 + lane] + sa[g][k] * sWn[k * 64 + lane];
  }
  xout[(size_t)n * 64 + lane] = acc;
  xb[(size_t)n * 64 + lane] = __builtin_bit_cast(unsigned short, (__bf16)acc);
}

// ---------------- W_fc prep into MFMA-B LDS layout ----------------
__global__ __launch_bounds__(256) void k_wprep(const float* __restrict__ Wfc,
                                               unsigned short* __restrict__ Wt) {
  int idx = blockIdx.x * 256 + threadIdx.x;   // [0, 3*16384)
  int l = idx >> 14;
  int o = idx & 16383;
  int e = o & 7;
  int col = (o >> 3) & 63;
  int kg = (o >> 9) & 1;
  int ks = o >> 10;
  int k = ks * 16 + kg * 8 + e;
  float v = Wfc[((size_t)l * 257 + k) * 64 + col];
  Wt[idx] = __builtin_bit_cast(unsigned short, (__bf16)v);
}

// ---------------- edge update v11: v10 + FUSED next-layer aggregation ----------------
// k_agg re-gathered exactly the x[src] rows k_edge already loads (sfr), and
// k_edge now processes edges trg-SORTED -> segment-sum is a 5-step shfl_up
// segmented scan over the 32-lane tile. Last lane of each run (avg ~2/tile)
// scales by 1/deg[te] and atomicAdds its 32 cols into agg (cross-tile run
// splits handled by atomics). Replaces k_agg for layers 1,2 at zero extra
// gather cost. agg zeroed between k_conv (reader) and k_edge (accumulator).
template <int IN_BF16, int OUT_BF16, int AGG>
__global__ __launch_bounds__(256, 4) void k_edge(
    const unsigned short* __restrict__ xb, const int* __restrict__ srcp,
    const int* __restrict__ trgp, const int* __restrict__ eid,
    const void* ef_in, const unsigned short* __restrict__ Wt,
    const float* __restrict__ w256, const float* __restrict__ bfc,
    const float* __restrict__ deg, float* __restrict__ agg,
    void* ef_out) {
  __shared__ __align__(16) unsigned short sB[16384];  // 32KB: [ks][kg][col][8]

  int t = threadIdx.x;
  // ---- stage Wt -> LDS (linear, coalesced, L2-hot) ----
  {
    const u32x4* wg = (const u32x4*)Wt;
    u32x4* sb = (u32x4*)sB;
    #pragma unroll
    for (int i = 0; i < 8; i++) sb[t + 256 * i] = wg[t + 256 * i];
  }
  __syncthreads();
  const u32x4* sb4 = (const u32x4*)sB;

  int w = t >> 6;
  int lane = t & 63;
  int rl = lane & 31;   // position within tile == MFMA row == output col offset
  int kg = lane >> 5;   // k-half
  int e0 = (blockIdx.x * 4 + w) * 32;
  int e = e0 + rl;      // permuted position

  int se = srcp[e], te = trgp[e];
  int eidv = eid[e];    // original edge id

  // ---- issue ef load first ----
  u32x4 efr[4];
  if (IN_BF16) {
    const u32x4* eb = (const u32x4*)ef_in;
    #pragma unroll
    for (int j = 0; j < 4; j++) efr[j] = eb[(size_t)e * 8 + j * 2 + kg];
  } else {
    const float4* ef4 = (const float4*)ef_in;
    #pragma unroll
    for (int j = 0; j < 4; j++) {
      float4 a = ef4[(size_t)eidv * 16 + j * 4 + kg * 2];
      float4 b = ef4[(size_t)eidv * 16 + j * 4 + kg * 2 + 1];
      float f[8] = {a.x, a.y, a.z, a.w, b.x, b.y, b.z, b.w};
      efr[j] = pack8(f);
    }
  }

  // ---- x gathers: te near-broadcast (sorted), se random ----
  const u32x4* xq = (const u32x4*)xb;
  u32x4 sfr[4], tfr[4];
  #pragma unroll
  for (int j = 0; j < 4; j++) {
    sfr[j] = xq[(size_t)se * 8 + j * 2 + kg];
    tfr[j] = xq[(size_t)te * 8 + j * 2 + kg];
  }

  int col0 = rl, col1 = 32 + rl;
  float wv0 = w256[col0], wv1 = w256[col1];
  f32x16 acc0, acc1;
  {
    float b0 = bfc[col0], b1 = bfc[col1];
    #pragma unroll
    for (int r = 0; r < 16; r++) { acc0[r] = b0; acc1[r] = b1; }
  }

  // ---- ef MFMAs (k 0..63) ----
  #pragma unroll
  for (int ks = 0; ks < 4; ks++) {
    bf16x8 av = __builtin_bit_cast(bf16x8, efr[ks]);
    int bi = (ks * 2 + kg) * 64;
    acc0 = __builtin_amdgcn_mfma_f32_32x32x16_bf16(
        av, __builtin_bit_cast(bf16x8, sb4[bi + col0]), acc0, 0, 0, 0);
    acc1 = __builtin_amdgcn_mfma_f32_32x32x16_bf16(
        av, __builtin_bit_cast(bf16x8, sb4[bi + col1]), acc1, 0, 0, 0);
  }
  // ---- xs MFMAs (k 64..127) ----
  #pragma unroll
  for (int ks = 4; ks < 8; ks++) {
    bf16x8 av = __builtin_bit_cast(bf16x8, sfr[ks - 4]);
    int bi = (ks * 2 + kg) * 64;
    acc0 = __builtin_amdgcn_mfma_f32_32x32x16_bf16(
        av, __builtin_bit_cast(bf16x8, sb4[bi + col0]), acc0, 0, 0, 0);
    acc1 = __builtin_amdgcn_mfma_f32_32x32x16_bf16(
        av, __builtin_bit_cast(bf16x8, sb4[bi + col1]), acc1, 0, 0, 0);
  }
  // ---- xt MFMAs (k 128..191) ----
  #pragma unroll
  for (int ks = 8; ks < 12; ks++) {
    bf16x8 av = __builtin_bit_cast(bf16x8, tfr[ks - 8]);
    int bi = (ks * 2 + kg) * 64;
    acc0 = __builtin_amdgcn_mfma_f32_32x32x16_bf16(
        av, __builtin_bit_cast(bf16x8, sb4[bi + col0]), acc0, 0, 0, 0);
    acc1 = __builtin_amdgcn_mfma_f32_32x32x16_bf16(
        av, __builtin_bit_cast(bf16x8, sb4[bi + col1]), acc1, 0, 0, 0);
  }

  // ---- sim partials + |xs-xt| frags; capture relu'd xs for fused agg ----
  float dot = 0.f, n1 = 0.f, n2 = 0.f;
  u32x4 dfr[4];
  float rs[4][8];  // relu(xs) for segmented aggregation (AGG only)
  #pragma unroll
  for (int j = 0; j < 4; j++) {
    float fs[8], ft[8], fd[8];
    #pragma unroll
    for (int q = 0; q < 4; q++) {
      fs[2 * q] = bflo(sfr[j][q]); fs[2 * q + 1] = bfhi(sfr[j][q]);
      ft[2 * q] = bflo(tfr[j][q]); ft[2 * q + 1] = bfhi(tfr[j][q]);
    }
    #pragma unroll
    for (int c = 0; c < 8; c++) {
      dot = fmaf(fs[c], ft[c], dot);
      n1 = fmaf(fs[c], fs[c], n1);
      n2 = fmaf(ft[c], ft[c], n2);
      fd[c] = fabsf(fs[c] - ft[c]);
      if (AGG) rs[j][c] = fmaxf(fs[c], 0.f);
    }
    dfr[j] = pack8(fd);
  }

  // ---- fused aggregation: segmented scan over trg-runs, atomics at run end ----
  if (AGG) {
    // 5-step inclusive segmented scan across rl (runs contiguous by sort)
    #pragma unroll
    for (int d = 1; d <= 16; d <<= 1) {
      int tprev = __shfl_up(te, d);
      bool ok = (rl >= d) && (tprev == te);
      #pragma unroll
      for (int j = 0; j < 4; j++) {
        #pragma unroll
        for (int c = 0; c < 8; c++) {
          float pv = __shfl_up(rs[j][c], d);
          rs[j][c] += ok ? pv : 0.f;
        }
      }
    }
    int tnext = __shfl_down(te, 1);
    bool last = (rl == 31) || (tnext != te);
    if (last) {
      float inv = 1.0f / fmaxf(deg[te], 1.0f);
      float* ag = agg + (size_t)te * 64 + kg * 8;
      #pragma unroll
      for (int j = 0; j < 4; j++) {
        #pragma unroll
        for (int c = 0; c < 8; c++) {
          atomicAdd(&ag[j * 16 + c], rs[j][c] * inv);
        }
      }
    }
  }

  // ---- |xs-xt| MFMAs (k 192..255) ----
  #pragma unroll
  for (int ks = 12; ks < 16; ks++) {
    bf16x8 av = __builtin_bit_cast(bf16x8, dfr[ks - 12]);
    int bi = (ks * 2 + kg) * 64;
    acc0 = __builtin_amdgcn_mfma_f32_32x32x16_bf16(
        av, __builtin_bit_cast(bf16x8, sb4[bi + col0]), acc0, 0, 0, 0);
    acc1 = __builtin_amdgcn_mfma_f32_32x32x16_bf16(
        av, __builtin_bit_cast(bf16x8, sb4[bi + col1]), acc1, 0, 0, 0);
  }

  // ---- combine kg-halves -> sim; fold sim-column (k=256) into output ----
  dot += __shfl_xor(dot, 32);
  n1 += __shfl_xor(n1, 32);
  n2 += __shfl_xor(n2, 32);
  float sim = dot / fmaxf(sqrtf(n1) * sqrtf(n2), 1e-8f);

  // ---- store C: bf16 to permuted efb (linear), fp32 final scatter via eid ----
  #pragma unroll
  for (int r = 0; r < 16; r++) {
    int row = (r & 3) + 8 * (r >> 2) + 4 * kg;
    float s = __shfl(sim, row);
    float o0 = fmaf(s, wv0, acc0[r]);
    float o1 = fmaf(s, wv1, acc1[r]);
    if (OUT_BF16) {
      size_t base = (size_t)(e0 + row) * 64;
      unsigned short* ob = (unsigned short*)ef_out;
      ob[base + col0] = __builtin_bit_cast(unsigned short, (__bf16)o0);
      ob[base + col1] = __builtin_bit_cast(unsigned short, (__bf16)o1);
    } else {
      int er = __shfl(eidv, row);  // lane 'row' holds eid[e0+row]
      size_t base = (size_t)er * 64;
      float* of = (float*)ef_out;
      of[base + col0] = o0;
      of[base + col1] = o1;
    }
  }
}

extern "C" void kernel_launch(void* const* d_in, const int* in_sizes, int n_in,
                              void* d_out, int out_size, void* d_ws, size_t ws_size,
                              hipStream_t stream) {
  const float* x_in   = (const float*)d_in[0];
  const int*   ei     = (const int*)d_in[1];
  const float* ef_in  = (const float*)d_in[2];
  const float* W_self = (const float*)d_in[3];
  const float* W_nbr  = (const float*)d_in[4];
  const float* b_conv = (const float*)d_in[5];
  const float* W_fc   = (const float*)d_in[6];
  const float* b_fc   = (const float*)d_in[7];
  float* out = (float*)d_out;

  const int* src = ei;
  const int* trg = ei + NE;

  char* ws = (char*)d_ws;
  size_t off = 0;
  float* deg      = (float*)(ws + off); off += (((size_t)NN * 4) + 255) & ~(size_t)255;
  int*   rowstart = (int*)(ws + off);   off += (((size_t)(NN + 1) * 4) + 255) & ~(size_t)255;
  int*   cursor   = (int*)(ws + off);   off += (((size_t)NN * 4) + 255) & ~(size_t)255;
  int*   csr      = (int*)(ws + off);   off += (size_t)NE * 4;
  int*   eid      = (int*)(ws + off);   off += (size_t)NE * 4;
  int*   trgp     = (int*)(ws + off);   off += (size_t)NE * 4;
  float* agg      = (float*)(ws + off); off += (size_t)NN * 64 * 4;
  float* x_a      = (float*)(ws + off); off += (size_t)NN * 64 * 4;
  float* x_b      = (float*)(ws + off); off += (size_t)NN * 64 * 4;
  unsigned short* Wt  = (unsigned short*)(ws + off); off += (size_t)NL * 16384 * 2;
  unsigned short* efb = (unsigned short*)(ws + off); off += (size_t)NE * 64 * 2;
  unsigned short* xbm = (unsigned short*)(ws + off); off += (size_t)NN * 64 * 2;

  k_zero<<<(NN + 255) / 256, 256, 0, stream>>>(deg);
  k_deg<<<(NE + 255) / 256, 256, 0, stream>>>(trg, deg);
  k_scan<<<1, 1024, 0, stream>>>(deg, rowstart, cursor);
  k_fill<<<(NE + 255) / 256, 256, 0, stream>>>(src, trg, cursor, csr, eid, trgp);
  k_wprep<<<(NL * 16384) / 256, 256, 0, stream>>>(W_fc, Wt);
  k_xmir<<<(NN * 8 + 255) / 256, 256, 0, stream>>>(x_in, xbm);

  const float* xcur = x_in;
  float* xnext = x_a;

  for (int i = 0; i < NL; i++) {
    int relu = (i > 0) ? 1 : 0;
    if (i == 0) {
      // layer 0: agg from x_in mirror (overwrite semantics)
      k_agg<<<(NN * 8 + 255) / 256, 256, 0, stream>>>(xbm, rowstart, csr, agg, relu);
    }
    // layers 1,2: agg was accumulated by the previous k_edge (fused)
    k_conv<<<NN / 4, 256, 0, stream>>>(xcur, agg,
                                       W_self + (size_t)i * 4096,
                                       W_nbr + (size_t)i * 4096,
                                       b_conv + (size_t)i * 64,
                                       xnext, xbm, relu);
    if (i < NL - 1) {
      // zero agg before k_edge<i> accumulates layer i+1's aggregation
      k_zagg<<<(NN * 16 + 255) / 256, 256, 0, stream>>>(agg);
    }
    const unsigned short* Wti = Wt + (size_t)i * 16384;
    const float* w256 = W_fc + ((size_t)i * 257 + 256) * 64;
    const float* bfc = b_fc + (size_t)i * 64;
    if (i == 0) {
      k_edge<0, 1, 1><<<NE / 128, 256, 0, stream>>>(xbm, csr, trgp, eid, ef_in,
                                                    Wti, w256, bfc, deg, agg, efb);
    } else if (i == 1) {
      k_edge<1, 1, 1><<<NE / 128, 256, 0, stream>>>(xbm, csr, trgp, eid, efb,
                                                    Wti, w256, bfc, deg, agg, efb);
    } else {
      k_edge<1, 0, 0><<<NE / 128, 256, 0, stream>>>(xbm, csr, trgp, eid, efb,
                                                    Wti, w256, bfc, deg, agg, out);
    }
    xcur = xnext;
    xnext = (xnext == x_a) ? x_b : x_a;
  }
}

// Round 11
// 769.014 us; speedup vs baseline: 1.2137x; 1.2137x over previous
//
#include <hip/hip_runtime.h>

#define NN 50000
#define NE 800000
#define NL 3

typedef __bf16 bf16x8 __attribute__((ext_vector_type(8)));
typedef float f32x16 __attribute__((ext_vector_type(16)));
typedef unsigned int u32x4 __attribute__((ext_vector_type(4)));

// ---------------- zero degree array ----------------
__global__ __launch_bounds__(256) void k_zero(float* __restrict__ deg) {
  int i = blockIdx.x * 256 + threadIdx.x;
  if (i < NN) deg[i] = 0.f;
}

// ---------------- degree histogram ----------------
__global__ __launch_bounds__(256) void k_deg(const int* __restrict__ trg,
                                             float* __restrict__ deg) {
  int e = blockIdx.x * 256 + threadIdx.x;
  if (e < NE) atomicAdd(&deg[trg[e]], 1.0f);
}

// ---------------- exclusive scan of degrees -> CSR row starts ----------------
__global__ __launch_bounds__(1024) void k_scan(const float* __restrict__ deg,
                                               int* __restrict__ rowstart,
                                               int* __restrict__ cursor) {
  __shared__ int part[1024];
  int t = threadIdx.x;
  int t0 = t * 49, t1 = min(t0 + 49, NN);
  int s = 0;
  for (int i = t0; i < t1; i++) s += (int)deg[i];
  part[t] = s;
  __syncthreads();
  for (int off = 1; off < 1024; off <<= 1) {
    int vv = (t >= off) ? part[t - off] : 0;
    int v = part[t];
    __syncthreads();
    part[t] = v + vv;
    __syncthreads();
  }
  int run = part[t] - s;  // exclusive prefix
  for (int i = t0; i < t1; i++) {
    rowstart[i] = run;
    cursor[i] = run;
    run += (int)deg[i];
  }
  if (t == 1023) rowstart[NN] = NE;
}

// ---------------- CSR fill: bucket by trg; emit src/eid/trg per position ----------------
__global__ __launch_bounds__(256) void k_fill(const int* __restrict__ src,
                                              const int* __restrict__ trg,
                                              int* __restrict__ cursor,
                                              int* __restrict__ csr,
                                              int* __restrict__ eid,
                                              int* __restrict__ trgp) {
  int e = blockIdx.x * 256 + threadIdx.x;
  if (e < NE) {
    int tv = trg[e];
    int pos = atomicAdd(&cursor[tv], 1);
    csr[pos] = src[e];
    eid[pos] = e;
    trgp[pos] = tv;
  }
}

__device__ inline u32x4 pack8(const float* f) {
  u32x4 r;
  #pragma unroll
  for (int i = 0; i < 4; i++) {
    unsigned short lo = __builtin_bit_cast(unsigned short, (__bf16)f[2 * i]);
    unsigned short hi = __builtin_bit_cast(unsigned short, (__bf16)f[2 * i + 1]);
    r[i] = (unsigned)lo | ((unsigned)hi << 16);
  }
  return r;
}

__device__ inline float bflo(unsigned u) {
  return __builtin_bit_cast(float, u << 16);
}
__device__ inline float bfhi(unsigned u) {
  return __builtin_bit_cast(float, u & 0xffff0000u);
}

// ---------------- bf16 mirror of x_in (layer-0 gather source) ----------------
__global__ __launch_bounds__(256) void k_xmir(const float* __restrict__ x,
                                              unsigned short* __restrict__ xb) {
  int i = blockIdx.x * 256 + threadIdx.x;   // NN*8 items, 8 elems each
  if (i < NN * 8) {
    const float4* x4 = (const float4*)x;
    float4 a = x4[2 * i], b = x4[2 * i + 1];
    float f[8] = {a.x, a.y, a.z, a.w, b.x, b.y, b.z, b.w};
    ((u32x4*)xb)[i] = pack8(f);
  }
}

// ---------------- gather aggregation v3: depth-2 x-prefetch ----------------
__global__ __launch_bounds__(256) void k_agg(const unsigned short* __restrict__ xb,
                                             const int* __restrict__ rowstart,
                                             const int* __restrict__ csr,
                                             float* __restrict__ agg, int relu) {
  int i = blockIdx.x * 256 + threadIdx.x;
  if (i >= NN * 8) return;
  int n = i >> 3, q = i & 7;                 // chunk q: bf16 cols [8q, 8q+8)
  const u32x4* xq = (const u32x4*)xb;
  int b = rowstart[n], en = rowstart[n + 1];
  int nj = en - b;
  float acc[8] = {0.f, 0.f, 0.f, 0.f, 0.f, 0.f, 0.f, 0.f};
  u32x4 v0 = {}, v1 = {};
  if (nj > 0) v0 = xq[(size_t)csr[b] * 8 + q];
  if (nj > 1) v1 = xq[(size_t)csr[b + 1] * 8 + q];
  for (int j = 0; j < nj; j++) {
    u32x4 v = v0;
    v0 = v1;
    if (j + 2 < nj) v1 = xq[(size_t)csr[b + j + 2] * 8 + q];
    #pragma unroll
    for (int c = 0; c < 4; c++) {
      float lo = bflo(v[c]), hi = bfhi(v[c]);
      if (relu) { lo = fmaxf(lo, 0.f); hi = fmaxf(hi, 0.f); }
      acc[2 * c] += lo;
      acc[2 * c + 1] += hi;
    }
  }
  float inv = 1.0f / fmaxf((float)nj, 1.0f);
  float4 o0 = {acc[0] * inv, acc[1] * inv, acc[2] * inv, acc[3] * inv};
  float4 o1 = {acc[4] * inv, acc[5] * inv, acc[6] * inv, acc[7] * inv};
  float4* a4 = (float4*)agg;
  a4[(size_t)n * 16 + q * 2] = o0;
  a4[(size_t)n * 16 + q * 2 + 1] = o1;
}

// ---------------- node conv v2: chunked grid-stride, weights staged ONCE per block ----------------
// Old k_conv: 12500 blocks x 32KB weight staging = 400MB L2 reads/layer
// (~6.4M line-requests) -- the same request pathology R4 fixed in k_edge.
// Now 1024 blocks each stage once and loop a CONTIGUOUS chunk of node
// groups (locality preserved). sx/sa LDS broadcast replaced by
// __shfl(xv,k) with compile-time k (v_readlane -> SGPR in FMA): no
// in-loop barriers.
#define CONV_BLOCKS 1024

__global__ __launch_bounds__(256) void k_conv(const float* __restrict__ x,
                                              const float* __restrict__ agg,
                                              const float* __restrict__ Ws,
                                              const float* __restrict__ Wn,
                                              const float* __restrict__ bc,
                                              float* __restrict__ xout,
                                              unsigned short* __restrict__ xb,
                                              int relu) {
  __shared__ float sWs[64 * 64];
  __shared__ float sWn[64 * 64];
  int tid = threadIdx.x;
  for (int i = tid; i < 4096; i += 256) { sWs[i] = Ws[i]; sWn[i] = Wn[i]; }
  __syncthreads();
  int g = tid >> 6, lane = tid & 63;
  float bcv = bc[lane];
  const int ngroups = NN / 4;  // 12500
  int chunk = (ngroups + CONV_BLOCKS - 1) / CONV_BLOCKS;
  int g0 = blockIdx.x * chunk;
  int g1 = min(g0 + chunk, ngroups);
  for (int grp = g0; grp < g1; grp++) {
    int n = grp * 4 + g;
    float xv = x[(size_t)n * 64 + lane];
    if (relu) xv = fmaxf(xv, 0.f);
    float av = agg[(size_t)n * 64 + lane];
    float acc = bcv;
    #pragma unroll
    for (int k = 0; k < 64; k++) {
      acc += __shfl(xv, k) * sWs[k * 64 + lane] + __shfl(av, k) * sWn[k * 64 + lane];
    }
    xout[(size_t)n * 64 + lane] = acc;
    xb[(size_t)n * 64 + lane] = __builtin_bit_cast(unsigned short, (__bf16)acc);
  }
}

// ---------------- W_fc prep into MFMA-B LDS layout ----------------
__global__ __launch_bounds__(256) void k_wprep(const float* __restrict__ Wfc,
                                               unsigned short* __restrict__ Wt) {
  int idx = blockIdx.x * 256 + threadIdx.x;   // [0, 3*16384)
  int l = idx >> 14;
  int o = idx & 16383;
  int e = o & 7;
  int col = (o >> 3) & 63;
  int kg = (o >> 9) & 1;
  int ks = o >> 10;
  int k = ks * 16 + kg * 8 + e;
  float v = Wfc[((size_t)l * 257 + k) * 64 + col];
  Wt[idx] = __builtin_bit_cast(unsigned short, (__bf16)v);
}

// ---------------- edge update v10 (R9 form, fused-agg reverted) ----------------
// R10 lesson: fused aggregation's scalar atomicAdd drain multiplied write
// traffic 100->447MB (L2 RMW + line writeback per atomic) and doubled
// k_edge. Reverted to the proven v10: trg-sorted positions, Wt in LDS,
// one tile/wave.
template <int IN_BF16, int OUT_BF16>
__global__ __launch_bounds__(256, 4) void k_edge(
    const unsigned short* __restrict__ xb, const int* __restrict__ srcp,
    const int* __restrict__ trgp, const int* __restrict__ eid,
    const void* ef_in, const unsigned short* __restrict__ Wt,
    const float* __restrict__ w256, const float* __restrict__ bfc,
    void* ef_out) {
  __shared__ __align__(16) unsigned short sB[16384];  // 32KB: [ks][kg][col][8]

  int t = threadIdx.x;
  // ---- stage Wt -> LDS (linear, coalesced, L2-hot) ----
  {
    const u32x4* wg = (const u32x4*)Wt;
    u32x4* sb = (u32x4*)sB;
    #pragma unroll
    for (int i = 0; i < 8; i++) sb[t + 256 * i] = wg[t + 256 * i];
  }
  __syncthreads();
  const u32x4* sb4 = (const u32x4*)sB;

  int w = t >> 6;
  int lane = t & 63;
  int rl = lane & 31;   // position within tile == MFMA row == output col offset
  int kg = lane >> 5;   // k-half
  int e0 = (blockIdx.x * 4 + w) * 32;
  int e = e0 + rl;      // permuted position

  int se = srcp[e], te = trgp[e];
  int eidv = eid[e];    // original edge id

  // ---- issue ef load first ----
  u32x4 efr[4];
  if (IN_BF16) {
    const u32x4* eb = (const u32x4*)ef_in;
    #pragma unroll
    for (int j = 0; j < 4; j++) efr[j] = eb[(size_t)e * 8 + j * 2 + kg];
  } else {
    const float4* ef4 = (const float4*)ef_in;
    #pragma unroll
    for (int j = 0; j < 4; j++) {
      float4 a = ef4[(size_t)eidv * 16 + j * 4 + kg * 2];
      float4 b = ef4[(size_t)eidv * 16 + j * 4 + kg * 2 + 1];
      float f[8] = {a.x, a.y, a.z, a.w, b.x, b.y, b.z, b.w};
      efr[j] = pack8(f);
    }
  }

  // ---- x gathers: te near-broadcast (sorted), se random ----
  const u32x4* xq = (const u32x4*)xb;
  u32x4 sfr[4], tfr[4];
  #pragma unroll
  for (int j = 0; j < 4; j++) {
    sfr[j] = xq[(size_t)se * 8 + j * 2 + kg];
    tfr[j] = xq[(size_t)te * 8 + j * 2 + kg];
  }

  int col0 = rl, col1 = 32 + rl;
  float wv0 = w256[col0], wv1 = w256[col1];
  f32x16 acc0, acc1;
  {
    float b0 = bfc[col0], b1 = bfc[col1];
    #pragma unroll
    for (int r = 0; r < 16; r++) { acc0[r] = b0; acc1[r] = b1; }
  }

  // ---- ef MFMAs (k 0..63) ----
  #pragma unroll
  for (int ks = 0; ks < 4; ks++) {
    bf16x8 av = __builtin_bit_cast(bf16x8, efr[ks]);
    int bi = (ks * 2 + kg) * 64;
    acc0 = __builtin_amdgcn_mfma_f32_32x32x16_bf16(
        av, __builtin_bit_cast(bf16x8, sb4[bi + col0]), acc0, 0, 0, 0);
    acc1 = __builtin_amdgcn_mfma_f32_32x32x16_bf16(
        av, __builtin_bit_cast(bf16x8, sb4[bi + col1]), acc1, 0, 0, 0);
  }
  // ---- xs MFMAs (k 64..127) ----
  #pragma unroll
  for (int ks = 4; ks < 8; ks++) {
    bf16x8 av = __builtin_bit_cast(bf16x8, sfr[ks - 4]);
    int bi = (ks * 2 + kg) * 64;
    acc0 = __builtin_amdgcn_mfma_f32_32x32x16_bf16(
        av, __builtin_bit_cast(bf16x8, sb4[bi + col0]), acc0, 0, 0, 0);
    acc1 = __builtin_amdgcn_mfma_f32_32x32x16_bf16(
        av, __builtin_bit_cast(bf16x8, sb4[bi + col1]), acc1, 0, 0, 0);
  }
  // ---- xt MFMAs (k 128..191) ----
  #pragma unroll
  for (int ks = 8; ks < 12; ks++) {
    bf16x8 av = __builtin_bit_cast(bf16x8, tfr[ks - 8]);
    int bi = (ks * 2 + kg) * 64;
    acc0 = __builtin_amdgcn_mfma_f32_32x32x16_bf16(
        av, __builtin_bit_cast(bf16x8, sb4[bi + col0]), acc0, 0, 0, 0);
    acc1 = __builtin_amdgcn_mfma_f32_32x32x16_bf16(
        av, __builtin_bit_cast(bf16x8, sb4[bi + col1]), acc1, 0, 0, 0);
  }

  // ---- sim partials + |xs-xt| frags (from bf16-rounded values) ----
  float dot = 0.f, n1 = 0.f, n2 = 0.f;
  u32x4 dfr[4];
  #pragma unroll
  for (int j = 0; j < 4; j++) {
    float fs[8], ft[8], fd[8];
    #pragma unroll
    for (int q = 0; q < 4; q++) {
      fs[2 * q] = bflo(sfr[j][q]); fs[2 * q + 1] = bfhi(sfr[j][q]);
      ft[2 * q] = bflo(tfr[j][q]); ft[2 * q + 1] = bfhi(tfr[j][q]);
    }
    #pragma unroll
    for (int c = 0; c < 8; c++) {
      dot = fmaf(fs[c], ft[c], dot);
      n1 = fmaf(fs[c], fs[c], n1);
      n2 = fmaf(ft[c], ft[c], n2);
      fd[c] = fabsf(fs[c] - ft[c]);
    }
    dfr[j] = pack8(fd);
  }

  // ---- |xs-xt| MFMAs (k 192..255) ----
  #pragma unroll
  for (int ks = 12; ks < 16; ks++) {
    bf16x8 av = __builtin_bit_cast(bf16x8, dfr[ks - 12]);
    int bi = (ks * 2 + kg) * 64;
    acc0 = __builtin_amdgcn_mfma_f32_32x32x16_bf16(
        av, __builtin_bit_cast(bf16x8, sb4[bi + col0]), acc0, 0, 0, 0);
    acc1 = __builtin_amdgcn_mfma_f32_32x32x16_bf16(
        av, __builtin_bit_cast(bf16x8, sb4[bi + col1]), acc1, 0, 0, 0);
  }

  // ---- combine kg-halves -> sim; fold sim-column (k=256) into output ----
  dot += __shfl_xor(dot, 32);
  n1 += __shfl_xor(n1, 32);
  n2 += __shfl_xor(n2, 32);
  float sim = dot / fmaxf(sqrtf(n1) * sqrtf(n2), 1e-8f);

  // ---- store C: bf16 to permuted efb (linear), fp32 final scatter via eid ----
  #pragma unroll
  for (int r = 0; r < 16; r++) {
    int row = (r & 3) + 8 * (r >> 2) + 4 * kg;
    float s = __shfl(sim, row);
    float o0 = fmaf(s, wv0, acc0[r]);
    float o1 = fmaf(s, wv1, acc1[r]);
    if (OUT_BF16) {
      size_t base = (size_t)(e0 + row) * 64;
      unsigned short* ob = (unsigned short*)ef_out;
      ob[base + col0] = __builtin_bit_cast(unsigned short, (__bf16)o0);
      ob[base + col1] = __builtin_bit_cast(unsigned short, (__bf16)o1);
    } else {
      int er = __shfl(eidv, row);  // lane 'row' holds eid[e0+row]
      size_t base = (size_t)er * 64;
      float* of = (float*)ef_out;
      of[base + col0] = o0;
      of[base + col1] = o1;
    }
  }
}

extern "C" void kernel_launch(void* const* d_in, const int* in_sizes, int n_in,
                              void* d_out, int out_size, void* d_ws, size_t ws_size,
                              hipStream_t stream) {
  const float* x_in   = (const float*)d_in[0];
  const int*   ei     = (const int*)d_in[1];
  const float* ef_in  = (const float*)d_in[2];
  const float* W_self = (const float*)d_in[3];
  const float* W_nbr  = (const float*)d_in[4];
  const float* b_conv = (const float*)d_in[5];
  const float* W_fc   = (const float*)d_in[6];
  const float* b_fc   = (const float*)d_in[7];
  float* out = (float*)d_out;

  const int* src = ei;
  const int* trg = ei + NE;

  char* ws = (char*)d_ws;
  size_t off = 0;
  float* deg      = (float*)(ws + off); off += (((size_t)NN * 4) + 255) & ~(size_t)255;
  int*   rowstart = (int*)(ws + off);   off += (((size_t)(NN + 1) * 4) + 255) & ~(size_t)255;
  int*   cursor   = (int*)(ws + off);   off += (((size_t)NN * 4) + 255) & ~(size_t)255;
  int*   csr      = (int*)(ws + off);   off += (size_t)NE * 4;
  int*   eid      = (int*)(ws + off);   off += (size_t)NE * 4;
  int*   trgp     = (int*)(ws + off);   off += (size_t)NE * 4;
  float* agg      = (float*)(ws + off); off += (size_t)NN * 64 * 4;
  float* x_a      = (float*)(ws + off); off += (size_t)NN * 64 * 4;
  float* x_b      = (float*)(ws + off); off += (size_t)NN * 64 * 4;
  unsigned short* Wt  = (unsigned short*)(ws + off); off += (size_t)NL * 16384 * 2;
  unsigned short* efb = (unsigned short*)(ws + off); off += (size_t)NE * 64 * 2;
  unsigned short* xbm = (unsigned short*)(ws + off); off += (size_t)NN * 64 * 2;

  k_zero<<<(NN + 255) / 256, 256, 0, stream>>>(deg);
  k_deg<<<(NE + 255) / 256, 256, 0, stream>>>(trg, deg);
  k_scan<<<1, 1024, 0, stream>>>(deg, rowstart, cursor);
  k_fill<<<(NE + 255) / 256, 256, 0, stream>>>(src, trg, cursor, csr, eid, trgp);
  k_wprep<<<(NL * 16384) / 256, 256, 0, stream>>>(W_fc, Wt);
  k_xmir<<<(NN * 8 + 255) / 256, 256, 0, stream>>>(x_in, xbm);

  const float* xcur = x_in;
  float* xnext = x_a;

  for (int i = 0; i < NL; i++) {
    int relu = (i > 0) ? 1 : 0;
    k_agg<<<(NN * 8 + 255) / 256, 256, 0, stream>>>(xbm, rowstart, csr, agg, relu);
    k_conv<<<CONV_BLOCKS, 256, 0, stream>>>(xcur, agg,
                                            W_self + (size_t)i * 4096,
                                            W_nbr + (size_t)i * 4096,
                                            b_conv + (size_t)i * 64,
                                            xnext, xbm, relu);
    const unsigned short* Wti = Wt + (size_t)i * 16384;
    const float* w256 = W_fc + ((size_t)i * 257 + 256) * 64;
    const float* bfc = b_fc + (size_t)i * 64;
    if (i == 0) {
      k_edge<0, 1><<<NE / 128, 256, 0, stream>>>(xbm, csr, trgp, eid, ef_in,
                                                 Wti, w256, bfc, efb);
    } else if (i == 1) {
      k_edge<1, 1><<<NE / 128, 256, 0, stream>>>(xbm, csr, trgp, eid, efb,
                                                 Wti, w256, bfc, efb);
    } else {
      k_edge<1, 0><<<NE / 128, 256, 0, stream>>>(xbm, csr, trgp, eid, efb,
                                                 Wti, w256, bfc, out);
    }
    xcur = xnext;
    xnext = (xnext == x_a) ? x_b : x_a;
  }
}

// Round 12
// 738.561 us; speedup vs baseline: 1.2637x; 1.0412x over previous
//
#include <hip/hip_runtime.h>

#define NN 50000
#define NE 800000
#define NL 3

typedef __bf16 bf16x8 __attribute__((ext_vector_type(8)));
typedef float f32x16 __attribute__((ext_vector_type(16)));
typedef unsigned int u32x4 __attribute__((ext_vector_type(4)));

// ---------------- zero degree array ----------------
__global__ __launch_bounds__(256) void k_zero(float* __restrict__ deg) {
  int i = blockIdx.x * 256 + threadIdx.x;
  if (i < NN) deg[i] = 0.f;
}

// ---------------- degree histogram ----------------
__global__ __launch_bounds__(256) void k_deg(const int* __restrict__ trg,
                                             float* __restrict__ deg) {
  int e = blockIdx.x * 256 + threadIdx.x;
  if (e < NE) atomicAdd(&deg[trg[e]], 1.0f);
}

// ---------------- exclusive scan of degrees -> CSR row starts ----------------
__global__ __launch_bounds__(1024) void k_scan(const float* __restrict__ deg,
                                               int* __restrict__ rowstart,
                                               int* __restrict__ cursor) {
  __shared__ int part[1024];
  int t = threadIdx.x;
  int t0 = t * 49, t1 = min(t0 + 49, NN);
  int s = 0;
  for (int i = t0; i < t1; i++) s += (int)deg[i];
  part[t] = s;
  __syncthreads();
  for (int off = 1; off < 1024; off <<= 1) {
    int vv = (t >= off) ? part[t - off] : 0;
    int v = part[t];
    __syncthreads();
    part[t] = v + vv;
    __syncthreads();
  }
  int run = part[t] - s;  // exclusive prefix
  for (int i = t0; i < t1; i++) {
    rowstart[i] = run;
    cursor[i] = run;
    run += (int)deg[i];
  }
  if (t == 1023) rowstart[NN] = NE;
}

// ---------------- CSR fill: bucket by trg; emit src/eid/trg per position ----------------
__global__ __launch_bounds__(256) void k_fill(const int* __restrict__ src,
                                              const int* __restrict__ trg,
                                              int* __restrict__ cursor,
                                              int* __restrict__ csr,
                                              int* __restrict__ eid,
                                              int* __restrict__ trgp) {
  int e = blockIdx.x * 256 + threadIdx.x;
  if (e < NE) {
    int tv = trg[e];
    int pos = atomicAdd(&cursor[tv], 1);
    csr[pos] = src[e];
    eid[pos] = e;
    trgp[pos] = tv;
  }
}

__device__ inline u32x4 pack8(const float* f) {
  u32x4 r;
  #pragma unroll
  for (int i = 0; i < 4; i++) {
    unsigned short lo = __builtin_bit_cast(unsigned short, (__bf16)f[2 * i]);
    unsigned short hi = __builtin_bit_cast(unsigned short, (__bf16)f[2 * i + 1]);
    r[i] = (unsigned)lo | ((unsigned)hi << 16);
  }
  return r;
}

__device__ inline float bflo(unsigned u) {
  return __builtin_bit_cast(float, u << 16);
}
__device__ inline float bfhi(unsigned u) {
  return __builtin_bit_cast(float, u & 0xffff0000u);
}

// ---------------- bf16 mirror of x_in (layer-0 gather source) ----------------
__global__ __launch_bounds__(256) void k_xmir(const float* __restrict__ x,
                                              unsigned short* __restrict__ xb) {
  int i = blockIdx.x * 256 + threadIdx.x;   // NN*8 items, 8 elems each
  if (i < NN * 8) {
    const float4* x4 = (const float4*)x;
    float4 a = x4[2 * i], b = x4[2 * i + 1];
    float f[8] = {a.x, a.y, a.z, a.w, b.x, b.y, b.z, b.w};
    ((u32x4*)xb)[i] = pack8(f);
  }
}

// ---------------- gather aggregation v3: depth-2 x-prefetch ----------------
__global__ __launch_bounds__(256) void k_agg(const unsigned short* __restrict__ xb,
                                             const int* __restrict__ rowstart,
                                             const int* __restrict__ csr,
                                             float* __restrict__ agg, int relu) {
  int i = blockIdx.x * 256 + threadIdx.x;
  if (i >= NN * 8) return;
  int n = i >> 3, q = i & 7;                 // chunk q: bf16 cols [8q, 8q+8)
  const u32x4* xq = (const u32x4*)xb;
  int b = rowstart[n], en = rowstart[n + 1];
  int nj = en - b;
  float acc[8] = {0.f, 0.f, 0.f, 0.f, 0.f, 0.f, 0.f, 0.f};
  u32x4 v0 = {}, v1 = {};
  if (nj > 0) v0 = xq[(size_t)csr[b] * 8 + q];
  if (nj > 1) v1 = xq[(size_t)csr[b + 1] * 8 + q];
  for (int j = 0; j < nj; j++) {
    u32x4 v = v0;
    v0 = v1;
    if (j + 2 < nj) v1 = xq[(size_t)csr[b + j + 2] * 8 + q];
    #pragma unroll
    for (int c = 0; c < 4; c++) {
      float lo = bflo(v[c]), hi = bfhi(v[c]);
      if (relu) { lo = fmaxf(lo, 0.f); hi = fmaxf(hi, 0.f); }
      acc[2 * c] += lo;
      acc[2 * c + 1] += hi;
    }
  }
  float inv = 1.0f / fmaxf((float)nj, 1.0f);
  float4 o0 = {acc[0] * inv, acc[1] * inv, acc[2] * inv, acc[3] * inv};
  float4 o1 = {acc[4] * inv, acc[5] * inv, acc[6] * inv, acc[7] * inv};
  float4* a4 = (float4*)agg;
  a4[(size_t)n * 16 + q * 2] = o0;
  a4[(size_t)n * 16 + q * 2 + 1] = o1;
}

// ---------------- node conv (R9 form restored): LDS broadcast, 4 nodes/block ----------------
// R11 lesson: the shfl-based chunked variant cost +68us total (cross-lane
// ops serialized); this LDS-broadcast form is the measured-best k_conv.
__global__ __launch_bounds__(256) void k_conv(const float* __restrict__ x,
                                              const float* __restrict__ agg,
                                              const float* __restrict__ Ws,
                                              const float* __restrict__ Wn,
                                              const float* __restrict__ bc,
                                              float* __restrict__ xout,
                                              unsigned short* __restrict__ xb,
                                              int relu) {
  __shared__ float sWs[64 * 64];
  __shared__ float sWn[64 * 64];
  __shared__ float sx[4][64];
  __shared__ float sa[4][64];
  int tid = threadIdx.x;
  for (int i = tid; i < 4096; i += 256) { sWs[i] = Ws[i]; sWn[i] = Wn[i]; }
  int g = tid >> 6, lane = tid & 63;
  int n = blockIdx.x * 4 + g;
  float xv = x[(size_t)n * 64 + lane];
  if (relu) xv = fmaxf(xv, 0.f);
  sx[g][lane] = xv;
  sa[g][lane] = agg[(size_t)n * 64 + lane];
  __syncthreads();
  float acc = bc[lane];
  #pragma unroll
  for (int k = 0; k < 64; k++) {
    acc += sx[g][k] * sWs[k * 64 + lane] + sa[g][k] * sWn[k * 64 + lane];
  }
  xout[(size_t)n * 64 + lane] = acc;
  xb[(size_t)n * 64 + lane] = __builtin_bit_cast(unsigned short, (__bf16)acc);
}

// ---------------- W_fc prep into MFMA-B LDS layout ----------------
__global__ __launch_bounds__(256) void k_wprep(const float* __restrict__ Wfc,
                                               unsigned short* __restrict__ Wt) {
  int idx = blockIdx.x * 256 + threadIdx.x;   // [0, 3*16384)
  int l = idx >> 14;
  int o = idx & 16383;
  int e = o & 7;
  int col = (o >> 3) & 63;
  int kg = (o >> 9) & 1;
  int ks = o >> 10;
  int k = ks * 16 + kg * 8 + e;
  float v = Wfc[((size_t)l * 257 + k) * 64 + col];
  Wt[idx] = __builtin_bit_cast(unsigned short, (__bf16)v);
}

// ---------------- edge update v12: v10 + occupancy cap raised to 5 blocks/CU ----------------
// R11 counters: 115us, BW 27%, MfmaUtil 9%, VALU 23%, occ 37% -- latency
// bound, nothing saturated. Resource audit: VGPR 52 (allows 8+ waves/EU),
// LDS 32KB (allows 5 blocks/CU = 160KB), but launch_bounds(256,4) pinned 4
// blocks/CU. Raise to (256,5): +25% resident waves for latency hiding.
// Single change vs R9; VGPR budget 512/5=102 >= 52.
template <int IN_BF16, int OUT_BF16>
__global__ __launch_bounds__(256, 5) void k_edge(
    const unsigned short* __restrict__ xb, const int* __restrict__ srcp,
    const int* __restrict__ trgp, const int* __restrict__ eid,
    const void* ef_in, const unsigned short* __restrict__ Wt,
    const float* __restrict__ w256, const float* __restrict__ bfc,
    void* ef_out) {
  __shared__ __align__(16) unsigned short sB[16384];  // 32KB: [ks][kg][col][8]

  int t = threadIdx.x;
  // ---- stage Wt -> LDS (linear, coalesced, L2-hot) ----
  {
    const u32x4* wg = (const u32x4*)Wt;
    u32x4* sb = (u32x4*)sB;
    #pragma unroll
    for (int i = 0; i < 8; i++) sb[t + 256 * i] = wg[t + 256 * i];
  }
  __syncthreads();
  const u32x4* sb4 = (const u32x4*)sB;

  int w = t >> 6;
  int lane = t & 63;
  int rl = lane & 31;   // position within tile == MFMA row == output col offset
  int kg = lane >> 5;   // k-half
  int e0 = (blockIdx.x * 4 + w) * 32;
  int e = e0 + rl;      // permuted position

  int se = srcp[e], te = trgp[e];
  int eidv = eid[e];    // original edge id

  // ---- issue ef load first ----
  u32x4 efr[4];
  if (IN_BF16) {
    const u32x4* eb = (const u32x4*)ef_in;
    #pragma unroll
    for (int j = 0; j < 4; j++) efr[j] = eb[(size_t)e * 8 + j * 2 + kg];
  } else {
    const float4* ef4 = (const float4*)ef_in;
    #pragma unroll
    for (int j = 0; j < 4; j++) {
      float4 a = ef4[(size_t)eidv * 16 + j * 4 + kg * 2];
      float4 b = ef4[(size_t)eidv * 16 + j * 4 + kg * 2 + 1];
      float f[8] = {a.x, a.y, a.z, a.w, b.x, b.y, b.z, b.w};
      efr[j] = pack8(f);
    }
  }

  // ---- x gathers: te near-broadcast (sorted), se random ----
  const u32x4* xq = (const u32x4*)xb;
  u32x4 sfr[4], tfr[4];
  #pragma unroll
  for (int j = 0; j < 4; j++) {
    sfr[j] = xq[(size_t)se * 8 + j * 2 + kg];
    tfr[j] = xq[(size_t)te * 8 + j * 2 + kg];
  }

  int col0 = rl, col1 = 32 + rl;
  float wv0 = w256[col0], wv1 = w256[col1];
  f32x16 acc0, acc1;
  {
    float b0 = bfc[col0], b1 = bfc[col1];
    #pragma unroll
    for (int r = 0; r < 16; r++) { acc0[r] = b0; acc1[r] = b1; }
  }

  // ---- ef MFMAs (k 0..63) ----
  #pragma unroll
  for (int ks = 0; ks < 4; ks++) {
    bf16x8 av = __builtin_bit_cast(bf16x8, efr[ks]);
    int bi = (ks * 2 + kg) * 64;
    acc0 = __builtin_amdgcn_mfma_f32_32x32x16_bf16(
        av, __builtin_bit_cast(bf16x8, sb4[bi + col0]), acc0, 0, 0, 0);
    acc1 = __builtin_amdgcn_mfma_f32_32x32x16_bf16(
        av, __builtin_bit_cast(bf16x8, sb4[bi + col1]), acc1, 0, 0, 0);
  }
  // ---- xs MFMAs (k 64..127) ----
  #pragma unroll
  for (int ks = 4; ks < 8; ks++) {
    bf16x8 av = __builtin_bit_cast(bf16x8, sfr[ks - 4]);
    int bi = (ks * 2 + kg) * 64;
    acc0 = __builtin_amdgcn_mfma_f32_32x32x16_bf16(
        av, __builtin_bit_cast(bf16x8, sb4[bi + col0]), acc0, 0, 0, 0);
    acc1 = __builtin_amdgcn_mfma_f32_32x32x16_bf16(
        av, __builtin_bit_cast(bf16x8, sb4[bi + col1]), acc1, 0, 0, 0);
  }
  // ---- xt MFMAs (k 128..191) ----
  #pragma unroll
  for (int ks = 8; ks < 12; ks++) {
    bf16x8 av = __builtin_bit_cast(bf16x8, tfr[ks - 8]);
    int bi = (ks * 2 + kg) * 64;
    acc0 = __builtin_amdgcn_mfma_f32_32x32x16_bf16(
        av, __builtin_bit_cast(bf16x8, sb4[bi + col0]), acc0, 0, 0, 0);
    acc1 = __builtin_amdgcn_mfma_f32_32x32x16_bf16(
        av, __builtin_bit_cast(bf16x8, sb4[bi + col1]), acc1, 0, 0, 0);
  }

  // ---- sim partials + |xs-xt| frags (from bf16-rounded values) ----
  float dot = 0.f, n1 = 0.f, n2 = 0.f;
  u32x4 dfr[4];
  #pragma unroll
  for (int j = 0; j < 4; j++) {
    float fs[8], ft[8], fd[8];
    #pragma unroll
    for (int q = 0; q < 4; q++) {
      fs[2 * q] = bflo(sfr[j][q]); fs[2 * q + 1] = bfhi(sfr[j][q]);
      ft[2 * q] = bflo(tfr[j][q]); ft[2 * q + 1] = bfhi(tfr[j][q]);
    }
    #pragma unroll
    for (int c = 0; c < 8; c++) {
      dot = fmaf(fs[c], ft[c], dot);
      n1 = fmaf(fs[c], fs[c], n1);
      n2 = fmaf(ft[c], ft[c], n2);
      fd[c] = fabsf(fs[c] - ft[c]);
    }
    dfr[j] = pack8(fd);
  }

  // ---- |xs-xt| MFMAs (k 192..255) ----
  #pragma unroll
  for (int ks = 12; ks < 16; ks++) {
    bf16x8 av = __builtin_bit_cast(bf16x8, dfr[ks - 12]);
    int bi = (ks * 2 + kg) * 64;
    acc0 = __builtin_amdgcn_mfma_f32_32x32x16_bf16(
        av, __builtin_bit_cast(bf16x8, sb4[bi + col0]), acc0, 0, 0, 0);
    acc1 = __builtin_amdgcn_mfma_f32_32x32x16_bf16(
        av, __builtin_bit_cast(bf16x8, sb4[bi + col1]), acc1, 0, 0, 0);
  }

  // ---- combine kg-halves -> sim; fold sim-column (k=256) into output ----
  dot += __shfl_xor(dot, 32);
  n1 += __shfl_xor(n1, 32);
  n2 += __shfl_xor(n2, 32);
  float sim = dot / fmaxf(sqrtf(n1) * sqrtf(n2), 1e-8f);

  // ---- store C: bf16 to permuted efb (linear), fp32 final scatter via eid ----
  #pragma unroll
  for (int r = 0; r < 16; r++) {
    int row = (r & 3) + 8 * (r >> 2) + 4 * kg;
    float s = __shfl(sim, row);
    float o0 = fmaf(s, wv0, acc0[r]);
    float o1 = fmaf(s, wv1, acc1[r]);
    if (OUT_BF16) {
      size_t base = (size_t)(e0 + row) * 64;
      unsigned short* ob = (unsigned short*)ef_out;
      ob[base + col0] = __builtin_bit_cast(unsigned short, (__bf16)o0);
      ob[base + col1] = __builtin_bit_cast(unsigned short, (__bf16)o1);
    } else {
      int er = __shfl(eidv, row);  // lane 'row' holds eid[e0+row]
      size_t base = (size_t)er * 64;
      float* of = (float*)ef_out;
      of[base + col0] = o0;
      of[base + col1] = o1;
    }
  }
}

extern "C" void kernel_launch(void* const* d_in, const int* in_sizes, int n_in,
                              void* d_out, int out_size, void* d_ws, size_t ws_size,
                              hipStream_t stream) {
  const float* x_in   = (const float*)d_in[0];
  const int*   ei     = (const int*)d_in[1];
  const float* ef_in  = (const float*)d_in[2];
  const float* W_self = (const float*)d_in[3];
  const float* W_nbr  = (const float*)d_in[4];
  const float* b_conv = (const float*)d_in[5];
  const float* W_fc   = (const float*)d_in[6];
  const float* b_fc   = (const float*)d_in[7];
  float* out = (float*)d_out;

  const int* src = ei;
  const int* trg = ei + NE;

  char* ws = (char*)d_ws;
  size_t off = 0;
  float* deg      = (float*)(ws + off); off += (((size_t)NN * 4) + 255) & ~(size_t)255;
  int*   rowstart = (int*)(ws + off);   off += (((size_t)(NN + 1) * 4) + 255) & ~(size_t)255;
  int*   cursor   = (int*)(ws + off);   off += (((size_t)NN * 4) + 255) & ~(size_t)255;
  int*   csr      = (int*)(ws + off);   off += (size_t)NE * 4;
  int*   eid      = (int*)(ws + off);   off += (size_t)NE * 4;
  int*   trgp     = (int*)(ws + off);   off += (size_t)NE * 4;
  float* agg      = (float*)(ws + off); off += (size_t)NN * 64 * 4;
  float* x_a      = (float*)(ws + off); off += (size_t)NN * 64 * 4;
  float* x_b      = (float*)(ws + off); off += (size_t)NN * 64 * 4;
  unsigned short* Wt  = (unsigned short*)(ws + off); off += (size_t)NL * 16384 * 2;
  unsigned short* efb = (unsigned short*)(ws + off); off += (size_t)NE * 64 * 2;
  unsigned short* xbm = (unsigned short*)(ws + off); off += (size_t)NN * 64 * 2;

  k_zero<<<(NN + 255) / 256, 256, 0, stream>>>(deg);
  k_deg<<<(NE + 255) / 256, 256, 0, stream>>>(trg, deg);
  k_scan<<<1, 1024, 0, stream>>>(deg, rowstart, cursor);
  k_fill<<<(NE + 255) / 256, 256, 0, stream>>>(src, trg, cursor, csr, eid, trgp);
  k_wprep<<<(NL * 16384) / 256, 256, 0, stream>>>(W_fc, Wt);
  k_xmir<<<(NN * 8 + 255) / 256, 256, 0, stream>>>(x_in, xbm);

  const float* xcur = x_in;
  float* xnext = x_a;

  for (int i = 0; i < NL; i++) {
    int relu = (i > 0) ? 1 : 0;
    k_agg<<<(NN * 8 + 255) / 256, 256, 0, stream>>>(xbm, rowstart, csr, agg, relu);
    k_conv<<<NN / 4, 256, 0, stream>>>(xcur, agg,
                                       W_self + (size_t)i * 4096,
                                       W_nbr + (size_t)i * 4096,
                                       b_conv + (size_t)i * 64,
                                       xnext, xbm, relu);
    const unsigned short* Wti = Wt + (size_t)i * 16384;
    const float* w256 = W_fc + ((size_t)i * 257 + 256) * 64;
    const float* bfc = b_fc + (size_t)i * 64;
    if (i == 0) {
      k_edge<0, 1><<<NE / 128, 256, 0, stream>>>(xbm, csr, trgp, eid, ef_in,
                                                 Wti, w256, bfc, efb);
    } else if (i == 1) {
      k_edge<1, 1><<<NE / 128, 256, 0, stream>>>(xbm, csr, trgp, eid, efb,
                                                 Wti, w256, bfc, efb);
    } else {
      k_edge<1, 0><<<NE / 128, 256, 0, stream>>>(xbm, csr, trgp, eid, efb,
                                                 Wti, w256, bfc, out);
    }
    xcur = xnext;
    xnext = (xnext == x_a) ? x_b : x_a;
  }
}

// Round 13
// 703.149 us; speedup vs baseline: 1.3274x; 1.0504x over previous
//
#include <hip/hip_runtime.h>

#define NN 50000
#define NE 800000
#define NL 3

typedef __bf16 bf16x8 __attribute__((ext_vector_type(8)));
typedef float f32x16 __attribute__((ext_vector_type(16)));
typedef unsigned int u32x4 __attribute__((ext_vector_type(4)));

// ---------------- zero degree array ----------------
__global__ __launch_bounds__(256) void k_zero(float* __restrict__ deg) {
  int i = blockIdx.x * 256 + threadIdx.x;
  if (i < NN) deg[i] = 0.f;
}

// ---------------- degree histogram ----------------
__global__ __launch_bounds__(256) void k_deg(const int* __restrict__ trg,
                                             float* __restrict__ deg) {
  int e = blockIdx.x * 256 + threadIdx.x;
  if (e < NE) atomicAdd(&deg[trg[e]], 1.0f);
}

// ---------------- exclusive scan of degrees -> CSR row starts ----------------
__global__ __launch_bounds__(1024) void k_scan(const float* __restrict__ deg,
                                               int* __restrict__ rowstart,
                                               int* __restrict__ cursor) {
  __shared__ int part[1024];
  int t = threadIdx.x;
  int t0 = t * 49, t1 = min(t0 + 49, NN);
  int s = 0;
  for (int i = t0; i < t1; i++) s += (int)deg[i];
  part[t] = s;
  __syncthreads();
  for (int off = 1; off < 1024; off <<= 1) {
    int vv = (t >= off) ? part[t - off] : 0;
    int v = part[t];
    __syncthreads();
    part[t] = v + vv;
    __syncthreads();
  }
  int run = part[t] - s;  // exclusive prefix
  for (int i = t0; i < t1; i++) {
    rowstart[i] = run;
    cursor[i] = run;
    run += (int)deg[i];
  }
  if (t == 1023) rowstart[NN] = NE;
}

// ---------------- CSR fill: bucket by trg; emit src/eid/trg per position ----------------
__global__ __launch_bounds__(256) void k_fill(const int* __restrict__ src,
                                              const int* __restrict__ trg,
                                              int* __restrict__ cursor,
                                              int* __restrict__ csr,
                                              int* __restrict__ eid,
                                              int* __restrict__ trgp) {
  int e = blockIdx.x * 256 + threadIdx.x;
  if (e < NE) {
    int tv = trg[e];
    int pos = atomicAdd(&cursor[tv], 1);
    csr[pos] = src[e];
    eid[pos] = e;
    trgp[pos] = tv;
  }
}

__device__ inline u32x4 pack8(const float* f) {
  u32x4 r;
  #pragma unroll
  for (int i = 0; i < 4; i++) {
    unsigned short lo = __builtin_bit_cast(unsigned short, (__bf16)f[2 * i]);
    unsigned short hi = __builtin_bit_cast(unsigned short, (__bf16)f[2 * i + 1]);
    r[i] = (unsigned)lo | ((unsigned)hi << 16);
  }
  return r;
}

__device__ inline float bflo(unsigned u) {
  return __builtin_bit_cast(float, u << 16);
}
__device__ inline float bfhi(unsigned u) {
  return __builtin_bit_cast(float, u & 0xffff0000u);
}

// ---------------- bf16 mirror of x_in (layer-0 gather source) ----------------
__global__ __launch_bounds__(256) void k_xmir(const float* __restrict__ x,
                                              unsigned short* __restrict__ xb) {
  int i = blockIdx.x * 256 + threadIdx.x;   // NN*8 items, 8 elems each
  if (i < NN * 8) {
    const float4* x4 = (const float4*)x;
    float4 a = x4[2 * i], b = x4[2 * i + 1];
    float f[8] = {a.x, a.y, a.z, a.w, b.x, b.y, b.z, b.w};
    ((u32x4*)xb)[i] = pack8(f);
  }
}

// ---------------- gather aggregation v3: depth-2 x-prefetch ----------------
__global__ __launch_bounds__(256) void k_agg(const unsigned short* __restrict__ xb,
                                             const int* __restrict__ rowstart,
                                             const int* __restrict__ csr,
                                             float* __restrict__ agg, int relu) {
  int i = blockIdx.x * 256 + threadIdx.x;
  if (i >= NN * 8) return;
  int n = i >> 3, q = i & 7;                 // chunk q: bf16 cols [8q, 8q+8)
  const u32x4* xq = (const u32x4*)xb;
  int b = rowstart[n], en = rowstart[n + 1];
  int nj = en - b;
  float acc[8] = {0.f, 0.f, 0.f, 0.f, 0.f, 0.f, 0.f, 0.f};
  u32x4 v0 = {}, v1 = {};
  if (nj > 0) v0 = xq[(size_t)csr[b] * 8 + q];
  if (nj > 1) v1 = xq[(size_t)csr[b + 1] * 8 + q];
  for (int j = 0; j < nj; j++) {
    u32x4 v = v0;
    v0 = v1;
    if (j + 2 < nj) v1 = xq[(size_t)csr[b + j + 2] * 8 + q];
    #pragma unroll
    for (int c = 0; c < 4; c++) {
      float lo = bflo(v[c]), hi = bfhi(v[c]);
      if (relu) { lo = fmaxf(lo, 0.f); hi = fmaxf(hi, 0.f); }
      acc[2 * c] += lo;
      acc[2 * c + 1] += hi;
    }
  }
  float inv = 1.0f / fmaxf((float)nj, 1.0f);
  float4 o0 = {acc[0] * inv, acc[1] * inv, acc[2] * inv, acc[3] * inv};
  float4 o1 = {acc[4] * inv, acc[5] * inv, acc[6] * inv, acc[7] * inv};
  float4* a4 = (float4*)agg;
  a4[(size_t)n * 16 + q * 2] = o0;
  a4[(size_t)n * 16 + q * 2 + 1] = o1;
}

// ---------------- node conv (measured-best form): LDS broadcast, 4 nodes/block ----------------
__global__ __launch_bounds__(256) void k_conv(const float* __restrict__ x,
                                              const float* __restrict__ agg,
                                              const float* __restrict__ Ws,
                                              const float* __restrict__ Wn,
                                              const float* __restrict__ bc,
                                              float* __restrict__ xout,
                                              unsigned short* __restrict__ xb,
                                              int relu) {
  __shared__ float sWs[64 * 64];
  __shared__ float sWn[64 * 64];
  __shared__ float sx[4][64];
  __shared__ float sa[4][64];
  int tid = threadIdx.x;
  for (int i = tid; i < 4096; i += 256) { sWs[i] = Ws[i]; sWn[i] = Wn[i]; }
  int g = tid >> 6, lane = tid & 63;
  int n = blockIdx.x * 4 + g;
  float xv = x[(size_t)n * 64 + lane];
  if (relu) xv = fmaxf(xv, 0.f);
  sx[g][lane] = xv;
  sa[g][lane] = agg[(size_t)n * 64 + lane];
  __syncthreads();
  float acc = bc[lane];
  #pragma unroll
  for (int k = 0; k < 64; k++) {
    acc += sx[g][k] * sWs[k * 64 + lane] + sa[g][k] * sWn[k * 64 + lane];
  }
  xout[(size_t)n * 64 + lane] = acc;
  xb[(size_t)n * 64 + lane] = __builtin_bit_cast(unsigned short, (__bf16)acc);
}

// ---------------- W_fc prep into MFMA-B LDS layout ----------------
__global__ __launch_bounds__(256) void k_wprep(const float* __restrict__ Wfc,
                                               unsigned short* __restrict__ Wt) {
  int idx = blockIdx.x * 256 + threadIdx.x;   // [0, 3*16384)
  int l = idx >> 14;
  int o = idx & 16383;
  int e = o & 7;
  int col = (o >> 3) & 63;
  int kg = (o >> 9) & 1;
  int ks = o >> 10;
  int k = ks * 16 + kg * 8 + e;
  float v = Wfc[((size_t)l * 257 + k) * 64 + col];
  Wt[idx] = __builtin_bit_cast(unsigned short, (__bf16)v);
}

// ---------------- edge update v10 (R9 exact restore — measured best: ~108-115us) ----------------
// R12 lesson: launch_bounds(256,5) did NOT raise occupancy (37->38.5%, the
// cap was never binding) and its codegen perturbation (VGPR 52->48) cost
// +10%. R10/R11/R12 all regressed vs this form -> v10 is the local optimum:
// trg-sorted positions (te-dedup), Wt in LDS (kills divergent B-reads),
// bf16 x-mirror + bf16 inter-layer ef, one tile/wave at (256,4).
template <int IN_BF16, int OUT_BF16>
__global__ __launch_bounds__(256, 4) void k_edge(
    const unsigned short* __restrict__ xb, const int* __restrict__ srcp,
    const int* __restrict__ trgp, const int* __restrict__ eid,
    const void* ef_in, const unsigned short* __restrict__ Wt,
    const float* __restrict__ w256, const float* __restrict__ bfc,
    void* ef_out) {
  __shared__ __align__(16) unsigned short sB[16384];  // 32KB: [ks][kg][col][8]

  int t = threadIdx.x;
  // ---- stage Wt -> LDS (linear, coalesced, L2-hot) ----
  {
    const u32x4* wg = (const u32x4*)Wt;
    u32x4* sb = (u32x4*)sB;
    #pragma unroll
    for (int i = 0; i < 8; i++) sb[t + 256 * i] = wg[t + 256 * i];
  }
  __syncthreads();
  const u32x4* sb4 = (const u32x4*)sB;

  int w = t >> 6;
  int lane = t & 63;
  int rl = lane & 31;   // position within tile == MFMA row == output col offset
  int kg = lane >> 5;   // k-half
  int e0 = (blockIdx.x * 4 + w) * 32;
  int e = e0 + rl;      // permuted position

  int se = srcp[e], te = trgp[e];
  int eidv = eid[e];    // original edge id

  // ---- issue ef load first ----
  u32x4 efr[4];
  if (IN_BF16) {
    const u32x4* eb = (const u32x4*)ef_in;
    #pragma unroll
    for (int j = 0; j < 4; j++) efr[j] = eb[(size_t)e * 8 + j * 2 + kg];
  } else {
    const float4* ef4 = (const float4*)ef_in;
    #pragma unroll
    for (int j = 0; j < 4; j++) {
      float4 a = ef4[(size_t)eidv * 16 + j * 4 + kg * 2];
      float4 b = ef4[(size_t)eidv * 16 + j * 4 + kg * 2 + 1];
      float f[8] = {a.x, a.y, a.z, a.w, b.x, b.y, b.z, b.w};
      efr[j] = pack8(f);
    }
  }

  // ---- x gathers: te near-broadcast (sorted), se random ----
  const u32x4* xq = (const u32x4*)xb;
  u32x4 sfr[4], tfr[4];
  #pragma unroll
  for (int j = 0; j < 4; j++) {
    sfr[j] = xq[(size_t)se * 8 + j * 2 + kg];
    tfr[j] = xq[(size_t)te * 8 + j * 2 + kg];
  }

  int col0 = rl, col1 = 32 + rl;
  float wv0 = w256[col0], wv1 = w256[col1];
  f32x16 acc0, acc1;
  {
    float b0 = bfc[col0], b1 = bfc[col1];
    #pragma unroll
    for (int r = 0; r < 16; r++) { acc0[r] = b0; acc1[r] = b1; }
  }

  // ---- ef MFMAs (k 0..63) ----
  #pragma unroll
  for (int ks = 0; ks < 4; ks++) {
    bf16x8 av = __builtin_bit_cast(bf16x8, efr[ks]);
    int bi = (ks * 2 + kg) * 64;
    acc0 = __builtin_amdgcn_mfma_f32_32x32x16_bf16(
        av, __builtin_bit_cast(bf16x8, sb4[bi + col0]), acc0, 0, 0, 0);
    acc1 = __builtin_amdgcn_mfma_f32_32x32x16_bf16(
        av, __builtin_bit_cast(bf16x8, sb4[bi + col1]), acc1, 0, 0, 0);
  }
  // ---- xs MFMAs (k 64..127) ----
  #pragma unroll
  for (int ks = 4; ks < 8; ks++) {
    bf16x8 av = __builtin_bit_cast(bf16x8, sfr[ks - 4]);
    int bi = (ks * 2 + kg) * 64;
    acc0 = __builtin_amdgcn_mfma_f32_32x32x16_bf16(
        av, __builtin_bit_cast(bf16x8, sb4[bi + col0]), acc0, 0, 0, 0);
    acc1 = __builtin_amdgcn_mfma_f32_32x32x16_bf16(
        av, __builtin_bit_cast(bf16x8, sb4[bi + col1]), acc1, 0, 0, 0);
  }
  // ---- xt MFMAs (k 128..191) ----
  #pragma unroll
  for (int ks = 8; ks < 12; ks++) {
    bf16x8 av = __builtin_bit_cast(bf16x8, tfr[ks - 8]);
    int bi = (ks * 2 + kg) * 64;
    acc0 = __builtin_amdgcn_mfma_f32_32x32x16_bf16(
        av, __builtin_bit_cast(bf16x8, sb4[bi + col0]), acc0, 0, 0, 0);
    acc1 = __builtin_amdgcn_mfma_f32_32x32x16_bf16(
        av, __builtin_bit_cast(bf16x8, sb4[bi + col1]), acc1, 0, 0, 0);
  }

  // ---- sim partials + |xs-xt| frags (from bf16-rounded values) ----
  float dot = 0.f, n1 = 0.f, n2 = 0.f;
  u32x4 dfr[4];
  #pragma unroll
  for (int j = 0; j < 4; j++) {
    float fs[8], ft[8], fd[8];
    #pragma unroll
    for (int q = 0; q < 4; q++) {
      fs[2 * q] = bflo(sfr[j][q]); fs[2 * q + 1] = bfhi(sfr[j][q]);
      ft[2 * q] = bflo(tfr[j][q]); ft[2 * q + 1] = bfhi(tfr[j][q]);
    }
    #pragma unroll
    for (int c = 0; c < 8; c++) {
      dot = fmaf(fs[c], ft[c], dot);
      n1 = fmaf(fs[c], fs[c], n1);
      n2 = fmaf(ft[c], ft[c], n2);
      fd[c] = fabsf(fs[c] - ft[c]);
    }
    dfr[j] = pack8(fd);
  }

  // ---- |xs-xt| MFMAs (k 192..255) ----
  #pragma unroll
  for (int ks = 12; ks < 16; ks++) {
    bf16x8 av = __builtin_bit_cast(bf16x8, dfr[ks - 12]);
    int bi = (ks * 2 + kg) * 64;
    acc0 = __builtin_amdgcn_mfma_f32_32x32x16_bf16(
        av, __builtin_bit_cast(bf16x8, sb4[bi + col0]), acc0, 0, 0, 0);
    acc1 = __builtin_amdgcn_mfma_f32_32x32x16_bf16(
        av, __builtin_bit_cast(bf16x8, sb4[bi + col1]), acc1, 0, 0, 0);
  }

  // ---- combine kg-halves -> sim; fold sim-column (k=256) into output ----
  dot += __shfl_xor(dot, 32);
  n1 += __shfl_xor(n1, 32);
  n2 += __shfl_xor(n2, 32);
  float sim = dot / fmaxf(sqrtf(n1) * sqrtf(n2), 1e-8f);

  // ---- store C: bf16 to permuted efb (linear), fp32 final scatter via eid ----
  #pragma unroll
  for (int r = 0; r < 16; r++) {
    int row = (r & 3) + 8 * (r >> 2) + 4 * kg;
    float s = __shfl(sim, row);
    float o0 = fmaf(s, wv0, acc0[r]);
    float o1 = fmaf(s, wv1, acc1[r]);
    if (OUT_BF16) {
      size_t base = (size_t)(e0 + row) * 64;
      unsigned short* ob = (unsigned short*)ef_out;
      ob[base + col0] = __builtin_bit_cast(unsigned short, (__bf16)o0);
      ob[base + col1] = __builtin_bit_cast(unsigned short, (__bf16)o1);
    } else {
      int er = __shfl(eidv, row);  // lane 'row' holds eid[e0+row]
      size_t base = (size_t)er * 64;
      float* of = (float*)ef_out;
      of[base + col0] = o0;
      of[base + col1] = o1;
    }
  }
}

extern "C" void kernel_launch(void* const* d_in, const int* in_sizes, int n_in,
                              void* d_out, int out_size, void* d_ws, size_t ws_size,
                              hipStream_t stream) {
  const float* x_in   = (const float*)d_in[0];
  const int*   ei     = (const int*)d_in[1];
  const float* ef_in  = (const float*)d_in[2];
  const float* W_self = (const float*)d_in[3];
  const float* W_nbr  = (const float*)d_in[4];
  const float* b_conv = (const float*)d_in[5];
  const float* W_fc   = (const float*)d_in[6];
  const float* b_fc   = (const float*)d_in[7];
  float* out = (float*)d_out;

  const int* src = ei;
  const int* trg = ei + NE;

  char* ws = (char*)d_ws;
  size_t off = 0;
  float* deg      = (float*)(ws + off); off += (((size_t)NN * 4) + 255) & ~(size_t)255;
  int*   rowstart = (int*)(ws + off);   off += (((size_t)(NN + 1) * 4) + 255) & ~(size_t)255;
  int*   cursor   = (int*)(ws + off);   off += (((size_t)NN * 4) + 255) & ~(size_t)255;
  int*   csr      = (int*)(ws + off);   off += (size_t)NE * 4;
  int*   eid      = (int*)(ws + off);   off += (size_t)NE * 4;
  int*   trgp     = (int*)(ws + off);   off += (size_t)NE * 4;
  float* agg      = (float*)(ws + off); off += (size_t)NN * 64 * 4;
  float* x_a      = (float*)(ws + off); off += (size_t)NN * 64 * 4;
  float* x_b      = (float*)(ws + off); off += (size_t)NN * 64 * 4;
  unsigned short* Wt  = (unsigned short*)(ws + off); off += (size_t)NL * 16384 * 2;
  unsigned short* efb = (unsigned short*)(ws + off); off += (size_t)NE * 64 * 2;
  unsigned short* xbm = (unsigned short*)(ws + off); off += (size_t)NN * 64 * 2;

  k_zero<<<(NN + 255) / 256, 256, 0, stream>>>(deg);
  k_deg<<<(NE + 255) / 256, 256, 0, stream>>>(trg, deg);
  k_scan<<<1, 1024, 0, stream>>>(deg, rowstart, cursor);
  k_fill<<<(NE + 255) / 256, 256, 0, stream>>>(src, trg, cursor, csr, eid, trgp);
  k_wprep<<<(NL * 16384) / 256, 256, 0, stream>>>(W_fc, Wt);
  k_xmir<<<(NN * 8 + 255) / 256, 256, 0, stream>>>(x_in, xbm);

  const float* xcur = x_in;
  float* xnext = x_a;

  for (int i = 0; i < NL; i++) {
    int relu = (i > 0) ? 1 : 0;
    k_agg<<<(NN * 8 + 255) / 256, 256, 0, stream>>>(xbm, rowstart, csr, agg, relu);
    k_conv<<<NN / 4, 256, 0, stream>>>(xcur, agg,
                                       W_self + (size_t)i * 4096,
                                       W_nbr + (size_t)i * 4096,
                                       b_conv + (size_t)i * 64,
                                       xnext, xbm, relu);
    const unsigned short* Wti = Wt + (size_t)i * 16384;
    const float* w256 = W_fc + ((size_t)i * 257 + 256) * 64;
    const float* bfc = b_fc + (size_t)i * 64;
    if (i == 0) {
      k_edge<0, 1><<<NE / 128, 256, 0, stream>>>(xbm, csr, trgp, eid, ef_in,
                                                 Wti, w256, bfc, efb);
    } else if (i == 1) {
      k_edge<1, 1><<<NE / 128, 256, 0, stream>>>(xbm, csr, trgp, eid, efb,
                                                 Wti, w256, bfc, efb);
    } else {
      k_edge<1, 0><<<NE / 128, 256, 0, stream>>>(xbm, csr, trgp, eid, efb,
                                                 Wti, w256, bfc, out);
    }
    xcur = xnext;
    xnext = (xnext == x_a) ? x_b : x_a;
  }
}